// Round 6
// baseline (45.337 us; speedup 1.0000x reference)
//
#include <hip/hip_runtime.h>
#include <hip/hip_bf16.h>

#define B_   4
#define Hf   128
#define Wf   128
#define HC   32
#define WC   32
#define SR   15
#define PAD  7
#define FR   125
#define FRP  139      // padded pooled grid: 125 + 14

typedef float vfloat4 __attribute__((ext_vector_type(4)));

static __device__ __forceinline__ unsigned short f2bf(float x) {
    __hip_bfloat16 h = __float2bfloat16(x);
    unsigned short u; __builtin_memcpy(&u, &h, 2); return u;
}

static __device__ __forceinline__ float mrg(float x, float y, bool hi, int m) {
    float u0 = hi ? x : y;
    float t  = __shfl_xor(u0, m, 64);
    return (hi ? y : x) + t;
}

// ---- fused pooling ----
// blocks [0, 4*18*18): f_r_pad = pad(avg_pool(in1,4,1), 7) -> (4,139,139,128) bf16
// blocks [1296, 1808): f_c     = avg_pool(in0,4,4)         -> (4,32,32,128)  fp32
__global__ __launch_bounds__(256) void pool_fused(const float* __restrict__ in0,
                                                  const float* __restrict__ in1,
                                                  float* __restrict__ fc,
                                                  unsigned short* __restrict__ fr16) {
    int bid = blockIdx.x;
    if (bid < 4 * 18 * 18) {
        int yt = bid % 18;
        int xt = (bid / 18) % 18;
        int b  = bid / (18 * 18);
        int c4 = threadIdx.x & 31;
        int x  = xt * 8 + (threadIdx.x >> 5);    // padded x, 0..143
        if (x >= FRP) return;
        int y0 = yt * 8;
        bool xin = (x >= PAD) && (x < PAD + FR);

        float4 h[11];
        if (xin) {
            int xi = x - PAD;
            const float4* base = reinterpret_cast<const float4*>(in1) + (b * Hf * Wf) * 32 + c4;
#pragma unroll
            for (int k = 0; k < 11; ++k) {
                int r = y0 - PAD + k;
                r = r < 0 ? 0 : (r > Hf - 1 ? Hf - 1 : r);
                float4 s = make_float4(0.f, 0.f, 0.f, 0.f);
#pragma unroll
                for (int dx = 0; dx < 4; ++dx) {
                    float4 v = base[(r * Wf + xi + dx) * 32];
                    s.x += v.x; s.y += v.y; s.z += v.z; s.w += v.w;
                }
                h[k] = s;
            }
        }
        const float s = 1.0f / 16.0f;
        ushort4* fr4 = reinterpret_cast<ushort4*>(fr16);
#pragma unroll
        for (int yy = 0; yy < 8; ++yy) {
            int y = y0 + yy;
            if (y >= FRP) continue;
            ushort4 o = make_ushort4(0, 0, 0, 0);
            if (xin && y >= PAD && y < PAD + FR) {
                o.x = f2bf((h[yy].x + h[yy+1].x + h[yy+2].x + h[yy+3].x) * s);
                o.y = f2bf((h[yy].y + h[yy+1].y + h[yy+2].y + h[yy+3].y) * s);
                o.z = f2bf((h[yy].z + h[yy+1].z + h[yy+2].z + h[yy+3].z) * s);
                o.w = f2bf((h[yy].w + h[yy+1].w + h[yy+2].w + h[yy+3].w) * s);
            }
            fr4[((b * FRP + y) * FRP + x) * 32 + c4] = o;
        }
    } else {
        int t = (bid - 4 * 18 * 18) * 256 + threadIdx.x;   // 512 blocks
        int c4 = t & 31;
        int j  = (t >> 5) & 31;
        int i  = (t >> 10) & 31;
        int b  = t >> 15;
        const float4* in = reinterpret_cast<const float4*>(in0);
        int base = ((b * Hf + 4 * i) * Wf + 4 * j) * 32 + c4;
        float4 acc = make_float4(0.f, 0.f, 0.f, 0.f);
#pragma unroll
        for (int dy = 0; dy < 4; ++dy)
#pragma unroll
            for (int dx = 0; dx < 4; ++dx) {
                float4 v = in[base + dy * (Wf * 32) + dx * 32];
                acc.x += v.x; acc.y += v.y; acc.z += v.z; acc.w += v.w;
            }
        const float sc = 1.0f / 16.0f;
        acc.x *= sc; acc.y *= sc; acc.z *= sc; acc.w *= sc;
        reinterpret_cast<float4*>(fc)[t] = acc;
    }
}

// ---- correlation + leaky_relu + 4x4 replicate ----
// block per cell; 8 groups x 32 lanes; group g owns u = g, g+8
// fr is fully padded -> zero branches, 15 straight-line loads w/ immediate offsets
__global__ __launch_bounds__(256) void corr_kernel(const float* __restrict__ fc,
                                                   const unsigned short* __restrict__ fr16,
                                                   float* __restrict__ out) {
    int blk  = blockIdx.x;
    int cell = (blk & 7) * 512 + (blk >> 3);         // XCD swizzle (4096 % 8 == 0)
    int j = cell & 31;
    int i = (cell >> 5) & 31;
    int b = cell >> 10;

    int tid = threadIdx.x;
    int g   = tid >> 5;
    int gl  = tid & 31;

    __shared__ float corr_rep[900];

    float4 f = reinterpret_cast<const float4*>(fc)[((b * HC + i) * WC + j) * 32 + gl];

    const uint2* frbase = reinterpret_cast<const uint2*>(fr16);
    bool h16 = gl & 16, h8 = gl & 8, h4 = gl & 4, h2 = gl & 2;
    int vidx = ((gl >> 4) & 1) * 8 + ((gl >> 3) & 1) * 4 + ((gl >> 2) & 1) * 2 + ((gl >> 1) & 1);

#pragma unroll
    for (int pass = 0; pass < 2; ++pass) {
        int u = g + pass * 8;
        if (u < SR) {
            int row = 4 * i + u;                     // padded coords, always in-bounds
            const uint2* p = frbase + ((b * FRP + row) * FRP + 4 * j) * 32 + gl;

            float a[16];
#pragma unroll
            for (int k = 0; k < 16; ++k) a[k] = 0.f;
#pragma unroll
            for (int v = 0; v < SR; ++v) {
                uint2 w = p[v * 32];
                float r0 = __uint_as_float(w.x << 16);
                float r1 = __uint_as_float(w.x & 0xffff0000u);
                float r2 = __uint_as_float(w.y << 16);
                float r3 = __uint_as_float(w.y & 0xffff0000u);
                a[v] = fmaf(f.x, r0, fmaf(f.y, r1, fmaf(f.z, r2, f.w * r3)));
            }

            float bb[8], cc[4], dd[2], e;
#pragma unroll
            for (int k = 0; k < 8; ++k) bb[k] = mrg(a[k], a[k + 8], h16, 16);
#pragma unroll
            for (int k = 0; k < 4; ++k) cc[k] = mrg(bb[k], bb[k + 4], h8, 8);
#pragma unroll
            for (int k = 0; k < 2; ++k) dd[k] = mrg(cc[k], cc[k + 2], h4, 4);
            e = mrg(dd[0], dd[1], h2, 2);
            e += __shfl_xor(e, 1, 64);

            if (vidx < SR) {
                float cv = e * (1.0f / 128.0f);
                float val = cv > 0.f ? cv : 0.1f * cv;
                int uvq = u * SR + vidx;
                int c0 = (gl & 1) * 225;
                corr_rep[c0 + uvq] = val;
                corr_rep[c0 + 450 + uvq] = val;
            }
        }
    }
    __syncthreads();

    if (tid < SR * SR) {
        vfloat4 val = *reinterpret_cast<const vfloat4*>(&corr_rep[4 * tid]);
        vfloat4* out4 = reinterpret_cast<vfloat4*>(out);
        long pix   = (long)(b * Hf + 4 * i) * Wf + 4 * j;
        long base4 = pix * (SR * SR) / 4;
#pragma unroll
        for (int di = 0; di < 4; ++di)
            __builtin_nontemporal_store(val, &out4[base4 + di * (Wf * SR * SR / 4) + tid]);
    }
}

extern "C" void kernel_launch(void* const* d_in, const int* in_sizes, int n_in,
                              void* d_out, int out_size, void* d_ws, size_t ws_size,
                              hipStream_t stream) {
    const float* f0 = (const float*)d_in[0];
    const float* f1 = (const float*)d_in[1];
    float* out = (float*)d_out;

    float* fc = (float*)d_ws;                                        // 2 MB fp32
    unsigned short* fr16 = (unsigned short*)(fc + B_ * HC * WC * 128);  // 19.8 MB bf16, padded

    pool_fused<<<4 * 18 * 18 + 512, 256, 0, stream>>>(f0, f1, fc, fr16);
    corr_kernel<<<B_ * HC * WC, 256, 0, stream>>>(fc, fr16, out);
}